// Round 11
// baseline (342.854 us; speedup 1.0000x reference)
//
#include <hip/hip_runtime.h>
#include <hip/hip_bf16.h>
#include <cstdint>

#define NQ 22500
#define NV 13294
#define EMBED 256

typedef short bf16x8 __attribute__((ext_vector_type(8)));
typedef float f32x4  __attribute__((ext_vector_type(4)));

// static level metadata: shapes [[100,100],[50,50],[25,25],[13,13]]
__device__ __forceinline__ int lvlH(int l) { return l==0?100 : l==1?50 : l==2?25 : 13; }
__device__ __forceinline__ int lvlW(int l) { return l==0?100 : l==1?50 : l==2?25 : 13; }
__device__ __forceinline__ int lvlStart(int l) { return l==0?0 : l==1?10000 : l==2?12500 : 13125; }

// manual f32 -> bf16 round-to-nearest-even
__device__ __forceinline__ ushort f2bf(float x) {
    uint32_t u = __float_as_uint(x);
    uint32_t r = (u + 0x7FFFu + ((u >> 16) & 1u)) >> 16;
    return (ushort)r;
}

// ---------------------------------------------------------------------------
// prep: blockIdx.y selects job, grid-stride within.
// ---------------------------------------------------------------------------
__global__ __launch_bounds__(256) void prep_kernel(
    const float* __restrict__ value, const float* __restrict__ query,
    const float* __restrict__ Wv, const float* __restrict__ Wo,
    const float* __restrict__ Wa, const float* __restrict__ Wt,
    ushort* __restrict__ val_bf, ushort* __restrict__ q_bf,
    ushort* __restrict__ Wv_t, ushort* __restrict__ Wo_t,
    ushort* __restrict__ Wa_t, ushort* __restrict__ Wt_t)
{
    const int y = blockIdx.y;
    const int idx0 = blockIdx.x * 256 + threadIdx.x;
    const int stride = gridDim.x * 256;

    if (y == 0) {
        for (int i = idx0; i < (NV * 256) / 4; i += stride) {
            float4 v = ((const float4*)value)[i];
            ushort4 o; o.x = f2bf(v.x); o.y = f2bf(v.y); o.z = f2bf(v.z); o.w = f2bf(v.w);
            ((ushort4*)val_bf)[i] = o;
        }
    } else if (y == 1) {
        for (int i = idx0; i < (NQ * 256) / 4; i += stride) {
            float4 v = ((const float4*)query)[i];
            ushort4 o; o.x = f2bf(v.x); o.y = f2bf(v.y); o.z = f2bf(v.z); o.w = f2bf(v.w);
            ((ushort4*)q_bf)[i] = o;
        }
    } else if (y == 2) {
        for (int i = idx0; i < 256 * 256; i += stride) {
            int n = i & 255, k = i >> 8;
            Wv_t[n * 256 + k] = f2bf(Wv[k * 256 + n]);
        }
    } else if (y == 3) {
        for (int i = idx0; i < 512 * 256; i += stride) {
            int n = i & 511, k = i >> 9;
            Wo_t[n * 256 + k] = f2bf(Wo[k * 512 + n]);
        }
    } else if (y == 4) {
        for (int i = idx0; i < 256 * 256; i += stride) {
            int n = i & 255, k = i >> 8;
            Wa_t[n * 256 + k] = f2bf(Wa[k * 256 + n]);
        }
    } else {
        for (int i = idx0; i < 256 * 256; i += stride) {
            int n = i & 255, k = i >> 8;
            Wt_t[n * 256 + k] = f2bf(Wt[k * 256 + n]);
        }
    }
}

// ---------------------------------------------------------------------------
// bf16 MFMA GEMM v2: C(MxN) = A(Mx256 bf16) @ Bt(Nx256 bf16)^T + bias [+ R]
// 128x64 tile, BK=64, 4 waves; wave w owns rows w*32..w*32+31 x all 64 cols
// (2 mi x 4 ni frags of 16x16x32). LDS rows padded to 72 ushorts (144 B):
// fragment ds_read_b128 lands 2-way max on banks (free), 16B-aligned.
// Fragment/epilogue index maps identical to the R5-verified kernel.
// ---------------------------------------------------------------------------
template<bool RESID, bool OUT_BF16>
__global__ __launch_bounds__(256) void gemm_bf16(
    const ushort* __restrict__ A,   // M x 256, row-major bf16
    const ushort* __restrict__ Bt,  // N x 256, row-major bf16 (pre-transposed)
    const float* __restrict__ bias, const float* __restrict__ R,
    void* __restrict__ Cv, int M, int N)
{
    __shared__ __align__(16) ushort As[128][72];   // 18432 B
    __shared__ __align__(16) ushort Bs[64][72];    //  9216 B

    const int tid  = threadIdx.x;
    const int row0 = blockIdx.x * 128;
    const int col0 = blockIdx.y * 64;
    const int wave = tid >> 6, lane = tid & 63;
    const int r = lane & 15, g = lane >> 4;

    // staging assignments
    const int ar = tid >> 1, ac = (tid & 1) * 32;   // A: 2 thr/row, 4 uint4 each
    const int br = tid >> 2, bc = (tid & 3) * 16;   // B: 4 thr/row, 2 uint4 each
    const bool aok = (row0 + ar) < M;
    const ushort* Aptr = A + (size_t)(row0 + ar) * 256 + ac;
    const ushort* Bptr = Bt + (size_t)(col0 + br) * 256 + bc;

    f32x4 acc[2][4] = {};

    for (int k0 = 0; k0 < 256; k0 += 64) {
        uint4 av[4], bv[2];
#pragma unroll
        for (int j = 0; j < 4; ++j)
            av[j] = aok ? *(const uint4*)(Aptr + k0 + j * 8) : make_uint4(0, 0, 0, 0);
#pragma unroll
        for (int j = 0; j < 2; ++j)
            bv[j] = *(const uint4*)(Bptr + k0 + j * 8);

#pragma unroll
        for (int j = 0; j < 4; ++j)
            *(uint4*)&As[ar][ac + j * 8] = av[j];
#pragma unroll
        for (int j = 0; j < 2; ++j)
            *(uint4*)&Bs[br][bc + j * 8] = bv[j];
        __syncthreads();

#pragma unroll
        for (int kk = 0; kk < 2; ++kk) {
            const int kc = kk * 32 + g * 8;
            bf16x8 a0 = *(const bf16x8*)&As[wave * 32 + r][kc];
            bf16x8 a1 = *(const bf16x8*)&As[wave * 32 + 16 + r][kc];
            bf16x8 b0 = *(const bf16x8*)&Bs[r][kc];
            bf16x8 b1 = *(const bf16x8*)&Bs[16 + r][kc];
            bf16x8 b2 = *(const bf16x8*)&Bs[32 + r][kc];
            bf16x8 b3 = *(const bf16x8*)&Bs[48 + r][kc];

            acc[0][0] = __builtin_amdgcn_mfma_f32_16x16x32_bf16(a0, b0, acc[0][0], 0, 0, 0);
            acc[0][1] = __builtin_amdgcn_mfma_f32_16x16x32_bf16(a0, b1, acc[0][1], 0, 0, 0);
            acc[0][2] = __builtin_amdgcn_mfma_f32_16x16x32_bf16(a0, b2, acc[0][2], 0, 0, 0);
            acc[0][3] = __builtin_amdgcn_mfma_f32_16x16x32_bf16(a0, b3, acc[0][3], 0, 0, 0);
            acc[1][0] = __builtin_amdgcn_mfma_f32_16x16x32_bf16(a1, b0, acc[1][0], 0, 0, 0);
            acc[1][1] = __builtin_amdgcn_mfma_f32_16x16x32_bf16(a1, b1, acc[1][1], 0, 0, 0);
            acc[1][2] = __builtin_amdgcn_mfma_f32_16x16x32_bf16(a1, b2, acc[1][2], 0, 0, 0);
            acc[1][3] = __builtin_amdgcn_mfma_f32_16x16x32_bf16(a1, b3, acc[1][3], 0, 0, 0);
        }
        __syncthreads();
    }

    // epilogue: C/D layout (verified m89/m91): col = lane&15, row = (lane>>4)*4 + j
#pragma unroll
    for (int mi = 0; mi < 2; ++mi)
#pragma unroll
        for (int ni = 0; ni < 4; ++ni) {
            const int col = col0 + ni * 16 + r;
            const float bb = bias[col];
#pragma unroll
            for (int j = 0; j < 4; ++j) {
                const int row = row0 + wave * 32 + mi * 16 + g * 4 + j;
                if (row < M) {
                    float o = acc[mi][ni][j] + bb;
                    if (RESID) o += R[(size_t)row * N + col];
                    if (OUT_BF16)
                        ((ushort*)Cv)[(size_t)row * N + col] = f2bf(o);
                    else
                        ((float*)Cv)[(size_t)row * N + col] = o;
                }
            }
        }
}

// ---------------------------------------------------------------------------
// Sampling kernel v3 (unchanged from R6-R9 review): one block per query,
// 256 threads = 8 heads x 32 lanes; bf16 v; conflict-free LDS; uint4 gathers.
// ---------------------------------------------------------------------------
__device__ __forceinline__ void fma8(float* acc, uint4 u, float w) {
    acc[0] += w * __uint_as_float(u.x << 16);
    acc[1] += w * __uint_as_float(u.x & 0xffff0000u);
    acc[2] += w * __uint_as_float(u.y << 16);
    acc[3] += w * __uint_as_float(u.y & 0xffff0000u);
    acc[4] += w * __uint_as_float(u.z << 16);
    acc[5] += w * __uint_as_float(u.z & 0xffff0000u);
    acc[6] += w * __uint_as_float(u.w << 16);
    acc[7] += w * __uint_as_float(u.w & 0xffff0000u);
}

__global__ __launch_bounds__(256) void sample_kernel(
    const ushort* __restrict__ v,       // (NV, 256) bf16, col = h*32 + c
    const float* __restrict__ off_raw,  // (NQ, 512)  h*64 + l*16 + p*2 + {x,y}
    const float* __restrict__ attn_raw, // (NQ, 256)  h*32 + (l*8+p)
    const float* __restrict__ rp,       // (NQ, 4, 2)
    ushort* __restrict__ agg)           // (NQ, 256) bf16
{
    __shared__ int4   idxs[8][32];
    __shared__ float4 wts[8][32];

    const int q    = blockIdx.x;
    const int tid  = threadIdx.x;
    const int h    = tid >> 5;
    const int lane = tid & 31;
    const int l    = lane >> 3;
    const int p    = lane & 7;

    // ---- Phase 1 ----
    const float ox = off_raw[(size_t)q * 512 + h * 64 + l * 16 + p * 2 + 0];
    const float oy = off_raw[(size_t)q * 512 + h * 64 + l * 16 + p * 2 + 1];
    const float rx = rp[(size_t)q * 8 + l * 2 + 0];
    const float ry = rp[(size_t)q * 8 + l * 2 + 1];
    const float Wl = (float)lvlW(l), Hl = (float)lvlH(l);
    const int   Wi = lvlW(l), Hi = lvlH(l), base = lvlStart(l);
    const float xf = rx * Wl + ox - 0.5f;
    const float yf = ry * Hl + oy - 0.5f;

    float logit = attn_raw[(size_t)q * 256 + h * 32 + lane];
    float m = logit;
#pragma unroll
    for (int s = 16; s; s >>= 1) m = fmaxf(m, __shfl_xor(m, s, 32));
    float e = __expf(logit - m);
    float ssum = e;
#pragma unroll
    for (int s = 16; s; s >>= 1) ssum += __shfl_xor(ssum, s, 32);
    const float w = e / ssum;

    const float x0f = floorf(xf), y0f = floorf(yf);
    const float fx = xf - x0f, fy = yf - y0f;
    const int x0 = (int)x0f, y0 = (int)y0f;
    const int x1 = x0 + 1, y1 = y0 + 1;

    const bool vx0 = (unsigned)x0 < (unsigned)Wi;
    const bool vx1 = (unsigned)x1 < (unsigned)Wi;
    const bool vy0 = (unsigned)y0 < (unsigned)Hi;
    const bool vy1 = (unsigned)y1 < (unsigned)Hi;
    const int cx0 = vx0 ? x0 : 0, cx1 = vx1 ? x1 : 0;
    const int cy0 = vy0 ? y0 : 0, cy1 = vy1 ? y1 : 0;

    int4 idx;
    idx.x = base + cy0 * Wi + cx0;
    idx.y = base + cy0 * Wi + cx1;
    idx.z = base + cy1 * Wi + cx0;
    idx.w = base + cy1 * Wi + cx1;
    float4 wv;
    wv.x = (vy0 && vx0) ? w * (1.f - fy) * (1.f - fx) : 0.f;
    wv.y = (vy0 && vx1) ? w * (1.f - fy) * fx         : 0.f;
    wv.z = (vy1 && vx0) ? w * fy * (1.f - fx)         : 0.f;
    wv.w = (vy1 && vx1) ? w * fy * fx                 : 0.f;

    idxs[h][lane] = idx;
    wts[h][lane]  = wv;
    __syncthreads();

    // ---- Phase 2 ----
    const int slot = lane & 7;            // 8 sample-slots
    const int cg   = lane >> 3;           // 4 channel-groups of 8 channels
    const ushort* vbase = v + h * 32 + cg * 8;

    float acc[8] = {};
#pragma unroll
    for (int i = 0; i < 4; ++i) {
        const int s = slot + i * 8;       // LDS addr s*16B -> bank slot*4 (conflict-free)
        const int4   id = idxs[h][s];
        const float4 ww = wts[h][s];
        uint4 c00 = *(const uint4*)(vbase + (size_t)id.x * 256);
        uint4 c01 = *(const uint4*)(vbase + (size_t)id.y * 256);
        uint4 c10 = *(const uint4*)(vbase + (size_t)id.z * 256);
        uint4 c11 = *(const uint4*)(vbase + (size_t)id.w * 256);
        fma8(acc, c00, ww.x);
        fma8(acc, c01, ww.y);
        fma8(acc, c10, ww.z);
        fma8(acc, c11, ww.w);
    }

    // reduce across the 8 slots (lane bits 0..2)
#pragma unroll
    for (int m8 = 1; m8 <= 4; m8 <<= 1)
#pragma unroll
        for (int j = 0; j < 8; ++j)
            acc[j] += __shfl_xor(acc[j], m8, 32);

    if (slot == 0) {
        ushort pk[8];
#pragma unroll
        for (int j = 0; j < 8; ++j) pk[j] = f2bf(acc[j]);
        *(uint4*)(agg + (size_t)q * 256 + h * 32 + cg * 8) = *(const uint4*)pk;
    }
}

// ---------------------------------------------------------------------------
extern "C" void kernel_launch(void* const* d_in, const int* in_sizes, int n_in,
                              void* d_out, int out_size, void* d_ws, size_t ws_size,
                              hipStream_t stream)
{
    const float* query   = (const float*)d_in[0];
    const float* value   = (const float*)d_in[1];
    const float* rp      = (const float*)d_in[2];
    // d_in[3] spatial_shapes, d_in[4] level_start_index: static, hardcoded
    const float* W_value = (const float*)d_in[5];
    const float* b_value = (const float*)d_in[6];
    const float* W_off   = (const float*)d_in[7];
    const float* b_off   = (const float*)d_in[8];
    const float* W_attn  = (const float*)d_in[9];
    const float* b_attn  = (const float*)d_in[10];
    const float* W_out   = (const float*)d_in[11];
    const float* b_out   = (const float*)d_in[12];
    float* out = (float*)d_out;

    // workspace layout (~96 MB)
    ushort* v_bf    = (ushort*)d_ws;                     // NV*256 bf16 (value proj out)
    float*  off_ws  = (float*)(v_bf + (size_t)NV * 256); // NQ*512 f32
    float*  attn_ws = off_ws + (size_t)NQ * 512;         // NQ*256 f32
    ushort* q_bf    = (ushort*)(attn_ws + (size_t)NQ * 256); // NQ*256 bf16
    ushort* val_bf  = q_bf + (size_t)NQ * 256;           // NV*256 bf16
    ushort* Wv_t    = val_bf + (size_t)NV * 256;         // 256*256
    ushort* Wo_t    = Wv_t + 256 * 256;                  // 512*256
    ushort* Wa_t    = Wo_t + 512 * 256;                  // 256*256
    ushort* Wt_t    = Wa_t + 256 * 256;                  // 256*256
    ushort* agg_bf  = q_bf;   // alias: q_bf dead after attn GEMM

    dim3 blk(256);

    prep_kernel<<<dim3(2048, 6), blk, 0, stream>>>(
        value, query, W_value, W_off, W_attn, W_out,
        val_bf, q_bf, Wv_t, Wo_t, Wa_t, Wt_t);

    // value projection: (NV,256) @ (256,256) -> bf16
    gemm_bf16<false, true><<<dim3((NV + 127) / 128, 4), blk, 0, stream>>>(
        val_bf, Wv_t, b_value, nullptr, v_bf, NV, 256);
    // sampling offsets: (NQ,256) @ (256,512) -> f32
    gemm_bf16<false, false><<<dim3((NQ + 127) / 128, 8), blk, 0, stream>>>(
        q_bf, Wo_t, b_off, nullptr, off_ws, NQ, 512);
    // attention logits: (NQ,256) @ (256,256) -> f32
    gemm_bf16<false, false><<<dim3((NQ + 127) / 128, 4), blk, 0, stream>>>(
        q_bf, Wa_t, b_attn, nullptr, attn_ws, NQ, 256);
    // bilinear sampling + weighted aggregation -> bf16 agg (reuses q_bf)
    sample_kernel<<<NQ, blk, 0, stream>>>(v_bf, off_ws, attn_ws, rp, agg_bf);
    // output projection + residual: (NQ,256) @ (256,256) + b + query
    gemm_bf16<true, false><<<dim3((NQ + 127) / 128, 4), blk, 0, stream>>>(
        agg_bf, Wt_t, b_out, query, out, NQ, 256);
}

// Round 14
// 308.214 us; speedup vs baseline: 1.1124x; 1.1124x over previous
//
#include <hip/hip_runtime.h>
#include <hip/hip_bf16.h>
#include <cstdint>

#define NQ 22500
#define NV 13294
#define EMBED 256

typedef short bf16x8 __attribute__((ext_vector_type(8)));
typedef float f32x4  __attribute__((ext_vector_type(4)));

// static level metadata: shapes [[100,100],[50,50],[25,25],[13,13]]
__device__ __forceinline__ int lvlH(int l) { return l==0?100 : l==1?50 : l==2?25 : 13; }
__device__ __forceinline__ int lvlW(int l) { return l==0?100 : l==1?50 : l==2?25 : 13; }
__device__ __forceinline__ int lvlStart(int l) { return l==0?0 : l==1?10000 : l==2?12500 : 13125; }

// manual f32 -> bf16 round-to-nearest-even
__device__ __forceinline__ ushort f2bf(float x) {
    uint32_t u = __float_as_uint(x);
    uint32_t r = (u + 0x7FFFu + ((u >> 16) & 1u)) >> 16;
    return (ushort)r;
}
__device__ __forceinline__ uint32_t pk2(float lo, float hi) {
    return (uint32_t)f2bf(lo) | ((uint32_t)f2bf(hi) << 16);
}

// ---------------------------------------------------------------------------
// prep_w: weights only (q/v conversion now happens inside GEMM staging).
//  y0: W_value (256x256) -> bf16 transposed Wv_t
//  y1: [W_off | W_attn] -> bf16 transposed concat Woa_t (768 x 256)
//  y2: W_out -> bf16 transposed Wt_t
//  y3: bias concat [b_off | b_attn] -> bias_oa (768 f32)
// ---------------------------------------------------------------------------
__global__ __launch_bounds__(256) void prep_w(
    const float* __restrict__ Wv, const float* __restrict__ Wo,
    const float* __restrict__ Wa, const float* __restrict__ Wt,
    const float* __restrict__ b_off, const float* __restrict__ b_attn,
    ushort* __restrict__ Wv_t, ushort* __restrict__ Woa_t,
    ushort* __restrict__ Wt_t, float* __restrict__ bias_oa)
{
    const int y = blockIdx.y;
    const int idx0 = blockIdx.x * 256 + threadIdx.x;
    const int stride = gridDim.x * 256;

    if (y == 0) {
        for (int i = idx0; i < 256 * 256; i += stride) {
            int n = i >> 8, k = i & 255;
            Wv_t[n * 256 + k] = f2bf(Wv[k * 256 + n]);
        }
    } else if (y == 1) {
        for (int i = idx0; i < 768 * 256; i += stride) {
            int n = i >> 8, k = i & 255;
            float w = (n < 512) ? Wo[k * 512 + n] : Wa[k * 256 + (n - 512)];
            Woa_t[n * 256 + k] = f2bf(w);
        }
    } else if (y == 2) {
        for (int i = idx0; i < 256 * 256; i += stride) {
            int n = i >> 8, k = i & 255;
            Wt_t[n * 256 + k] = f2bf(Wt[k * 256 + n]);
        }
    } else {
        for (int i = idx0; i < 768; i += stride)
            bias_oa[i] = (i < 512) ? b_off[i] : b_attn[i - 512];
    }
}

// ---------------------------------------------------------------------------
// bf16 MFMA GEMM: C(MxN) = A(Mx256) @ Bt(Nx256 bf16)^T + bias [+ R]
// A_F32: A is f32, converted to bf16 during LDS staging (saves prep pass).
// 128x64 tile, BK=64, 4 waves; wave w owns rows w*32..w*32+31 x 64 cols
// (2 mi x 4 ni frags of 16x16x32). LDS rows padded to 72 ushorts (144 B).
// Fragment/epilogue maps identical to the R5/R11-verified kernels.
// ---------------------------------------------------------------------------
template<bool A_F32, bool RESID, bool OUT_BF16>
__global__ __launch_bounds__(256) void gemm_bf16(
    const void* __restrict__ Av,    // M x 256: f32 (A_F32) or bf16
    const ushort* __restrict__ Bt,  // N x 256, row-major bf16 (pre-transposed)
    const float* __restrict__ bias, const float* __restrict__ R,
    void* __restrict__ Cv, int M, int N)
{
    __shared__ __align__(16) ushort As[128][72];   // 18432 B
    __shared__ __align__(16) ushort Bs[64][72];    //  9216 B

    const int tid  = threadIdx.x;
    const int row0 = blockIdx.x * 128;
    const int col0 = blockIdx.y * 64;
    const int wave = tid >> 6, lane = tid & 63;
    const int r = lane & 15, g = lane >> 4;

    // staging assignments
    const int ar = tid >> 1, ac = (tid & 1) * 32;   // A: 2 thr/row, 32 elems each
    const int br = tid >> 2, bc = (tid & 3) * 16;   // B: 4 thr/row, 16 elems each
    const bool aok = (row0 + ar) < M;

    const float*  Af = (const float*)Av;
    const ushort* Ab = (const ushort*)Av;
    const size_t  abase = (size_t)(row0 + ar) * 256 + ac;
    const ushort* Bptr = Bt + (size_t)(col0 + br) * 256 + bc;

    f32x4 acc[2][4] = {};

    for (int k0 = 0; k0 < 256; k0 += 64) {
        uint4 av[4], bv[2];
        if (A_F32) {
#pragma unroll
            for (int j = 0; j < 4; ++j) {
                if (aok) {
                    float4 f0 = *(const float4*)(Af + abase + k0 + j * 8);
                    float4 f1 = *(const float4*)(Af + abase + k0 + j * 8 + 4);
                    av[j].x = pk2(f0.x, f0.y); av[j].y = pk2(f0.z, f0.w);
                    av[j].z = pk2(f1.x, f1.y); av[j].w = pk2(f1.z, f1.w);
                } else av[j] = make_uint4(0, 0, 0, 0);
            }
        } else {
#pragma unroll
            for (int j = 0; j < 4; ++j)
                av[j] = aok ? *(const uint4*)(Ab + abase + k0 + j * 8)
                            : make_uint4(0, 0, 0, 0);
        }
#pragma unroll
        for (int j = 0; j < 2; ++j)
            bv[j] = *(const uint4*)(Bptr + k0 + j * 8);

#pragma unroll
        for (int j = 0; j < 4; ++j)
            *(uint4*)&As[ar][ac + j * 8] = av[j];
#pragma unroll
        for (int j = 0; j < 2; ++j)
            *(uint4*)&Bs[br][bc + j * 8] = bv[j];
        __syncthreads();

#pragma unroll
        for (int kk = 0; kk < 2; ++kk) {
            const int kc = kk * 32 + g * 8;
            bf16x8 a0 = *(const bf16x8*)&As[wave * 32 + r][kc];
            bf16x8 a1 = *(const bf16x8*)&As[wave * 32 + 16 + r][kc];
            bf16x8 b0 = *(const bf16x8*)&Bs[r][kc];
            bf16x8 b1 = *(const bf16x8*)&Bs[16 + r][kc];
            bf16x8 b2 = *(const bf16x8*)&Bs[32 + r][kc];
            bf16x8 b3 = *(const bf16x8*)&Bs[48 + r][kc];

            acc[0][0] = __builtin_amdgcn_mfma_f32_16x16x32_bf16(a0, b0, acc[0][0], 0, 0, 0);
            acc[0][1] = __builtin_amdgcn_mfma_f32_16x16x32_bf16(a0, b1, acc[0][1], 0, 0, 0);
            acc[0][2] = __builtin_amdgcn_mfma_f32_16x16x32_bf16(a0, b2, acc[0][2], 0, 0, 0);
            acc[0][3] = __builtin_amdgcn_mfma_f32_16x16x32_bf16(a0, b3, acc[0][3], 0, 0, 0);
            acc[1][0] = __builtin_amdgcn_mfma_f32_16x16x32_bf16(a1, b0, acc[1][0], 0, 0, 0);
            acc[1][1] = __builtin_amdgcn_mfma_f32_16x16x32_bf16(a1, b1, acc[1][1], 0, 0, 0);
            acc[1][2] = __builtin_amdgcn_mfma_f32_16x16x32_bf16(a1, b2, acc[1][2], 0, 0, 0);
            acc[1][3] = __builtin_amdgcn_mfma_f32_16x16x32_bf16(a1, b3, acc[1][3], 0, 0, 0);
        }
        __syncthreads();
    }

    // epilogue: C/D layout (verified m89/m91): col = lane&15, row = (lane>>4)*4 + j
#pragma unroll
    for (int mi = 0; mi < 2; ++mi)
#pragma unroll
        for (int ni = 0; ni < 4; ++ni) {
            const int col = col0 + ni * 16 + r;
            const float bb = bias[col];
#pragma unroll
            for (int j = 0; j < 4; ++j) {
                const int row = row0 + wave * 32 + mi * 16 + g * 4 + j;
                if (row < M) {
                    float o = acc[mi][ni][j] + bb;
                    if (RESID) o += R[(size_t)row * N + col];
                    if (OUT_BF16)
                        ((ushort*)Cv)[(size_t)row * N + col] = f2bf(o);
                    else
                        ((float*)Cv)[(size_t)row * N + col] = o;
                }
            }
        }
}

// ---------------------------------------------------------------------------
// Sampling kernel (R5-proven f32 v2 structure + bank-conflict fix):
// one block per query, 256 threads = 8 heads x 32 lanes.
// Phase 1: lane s (= l*8+p) computes softmax weight + 4 clamped corner
//          indices + 4 pre-multiplied weights -> LDS.
// Phase 2: 4 sample-slots x 8 channel-groups; float4 corner gathers
//          (full 128B line per head per corner), 16 FMA/iter, 8 iters.
//          LDS read order s = slot + i*4 -> 2-way banks max (free, m136);
//          was slot*8+i (8-way, 5.76M conflicts measured in R5).
//          Reduce shfl_xor 8,16; slot==0 stores bf16 agg.
// ---------------------------------------------------------------------------
__global__ __launch_bounds__(256) void sample_kernel(
    const float* __restrict__ v,        // (NV, 256) f32, col = h*32 + c
    const float* __restrict__ oa,       // (NQ, 768): [0,512)=off, [512,768)=attn
    const float* __restrict__ rp,       // (NQ, 4, 2)
    ushort* __restrict__ agg)           // (NQ, 256) bf16
{
    __shared__ int4   idxs[8][32];
    __shared__ float4 wts[8][32];

    const int q    = blockIdx.x;
    const int tid  = threadIdx.x;
    const int h    = tid >> 5;
    const int lane = tid & 31;
    const int l    = lane >> 3;
    const int p    = lane & 7;

    // ---- Phase 1 ----
    const float ox = oa[(size_t)q * 768 + h * 64 + l * 16 + p * 2 + 0];
    const float oy = oa[(size_t)q * 768 + h * 64 + l * 16 + p * 2 + 1];
    const float rx = rp[(size_t)q * 8 + l * 2 + 0];
    const float ry = rp[(size_t)q * 8 + l * 2 + 1];
    const float Wl = (float)lvlW(l), Hl = (float)lvlH(l);
    const int   Wi = lvlW(l), Hi = lvlH(l), base = lvlStart(l);
    const float xf = rx * Wl + ox - 0.5f;
    const float yf = ry * Hl + oy - 0.5f;

    float logit = oa[(size_t)q * 768 + 512 + h * 32 + lane];
    float m = logit;
#pragma unroll
    for (int s = 16; s; s >>= 1) m = fmaxf(m, __shfl_xor(m, s, 32));
    float e = __expf(logit - m);
    float ssum = e;
#pragma unroll
    for (int s = 16; s; s >>= 1) ssum += __shfl_xor(ssum, s, 32);
    const float w = e / ssum;

    const float x0f = floorf(xf), y0f = floorf(yf);
    const float fx = xf - x0f, fy = yf - y0f;
    const int x0 = (int)x0f, y0 = (int)y0f;
    const int x1 = x0 + 1, y1 = y0 + 1;

    const bool vx0 = (unsigned)x0 < (unsigned)Wi;
    const bool vx1 = (unsigned)x1 < (unsigned)Wi;
    const bool vy0 = (unsigned)y0 < (unsigned)Hi;
    const bool vy1 = (unsigned)y1 < (unsigned)Hi;
    const int cx0 = vx0 ? x0 : 0, cx1 = vx1 ? x1 : 0;
    const int cy0 = vy0 ? y0 : 0, cy1 = vy1 ? y1 : 0;

    int4 idx;
    idx.x = base + cy0 * Wi + cx0;
    idx.y = base + cy0 * Wi + cx1;
    idx.z = base + cy1 * Wi + cx0;
    idx.w = base + cy1 * Wi + cx1;
    float4 wv;
    wv.x = (vy0 && vx0) ? w * (1.f - fy) * (1.f - fx) : 0.f;
    wv.y = (vy0 && vx1) ? w * (1.f - fy) * fx         : 0.f;
    wv.z = (vy1 && vx0) ? w * fy * (1.f - fx)         : 0.f;
    wv.w = (vy1 && vx1) ? w * fy * fx                 : 0.f;

    idxs[h][lane] = idx;
    wts[h][lane]  = wv;
    __syncthreads();

    // ---- Phase 2 ----
    const int slot = lane >> 3;           // 4 sample-slots
    const int cg   = lane & 7;            // 8 channel-groups of 4 channels
    const float* vbase = v + h * 32 + cg * 4;

    float4 acc = make_float4(0.f, 0.f, 0.f, 0.f);
#pragma unroll
    for (int i = 0; i < 8; ++i) {
        const int s = slot + i * 4;       // conflict-free order (2-way max)
        const int4   id = idxs[h][s];
        const float4 ww = wts[h][s];
        const float4 v00 = *(const float4*)(vbase + (size_t)id.x * 256);
        const float4 v01 = *(const float4*)(vbase + (size_t)id.y * 256);
        const float4 v10 = *(const float4*)(vbase + (size_t)id.z * 256);
        const float4 v11 = *(const float4*)(vbase + (size_t)id.w * 256);
        acc.x += ww.x * v00.x + ww.y * v01.x + ww.z * v10.x + ww.w * v11.x;
        acc.y += ww.x * v00.y + ww.y * v01.y + ww.z * v10.y + ww.w * v11.y;
        acc.z += ww.x * v00.z + ww.y * v01.z + ww.z * v10.z + ww.w * v11.z;
        acc.w += ww.x * v00.w + ww.y * v01.w + ww.z * v10.w + ww.w * v11.w;
    }

    // reduce across the 4 sample-slots (lane bits 3,4)
#pragma unroll
    for (int s = 8; s <= 16; s <<= 1) {
        acc.x += __shfl_xor(acc.x, s, 32);
        acc.y += __shfl_xor(acc.y, s, 32);
        acc.z += __shfl_xor(acc.z, s, 32);
        acc.w += __shfl_xor(acc.w, s, 32);
    }

    if (slot == 0) {
        ushort4 pk;
        pk.x = f2bf(acc.x); pk.y = f2bf(acc.y); pk.z = f2bf(acc.z); pk.w = f2bf(acc.w);
        *(ushort4*)(agg + (size_t)q * 256 + h * 32 + cg * 4) = pk;
    }
}

// ---------------------------------------------------------------------------
extern "C" void kernel_launch(void* const* d_in, const int* in_sizes, int n_in,
                              void* d_out, int out_size, void* d_ws, size_t ws_size,
                              hipStream_t stream)
{
    const float* query   = (const float*)d_in[0];
    const float* value   = (const float*)d_in[1];
    const float* rp      = (const float*)d_in[2];
    // d_in[3] spatial_shapes, d_in[4] level_start_index: static, hardcoded
    const float* W_value = (const float*)d_in[5];
    const float* b_value = (const float*)d_in[6];
    const float* W_off   = (const float*)d_in[7];
    const float* b_off   = (const float*)d_in[8];
    const float* W_attn  = (const float*)d_in[9];
    const float* b_attn  = (const float*)d_in[10];
    const float* W_out   = (const float*)d_in[11];
    const float* b_out   = (const float*)d_in[12];
    float* out = (float*)d_out;

    // workspace layout (~95 MB)
    float*  v_ws    = (float*)d_ws;                      // NV*256 f32
    float*  oa_ws   = v_ws + (size_t)NV * 256;           // NQ*768 f32 (off|attn)
    ushort* agg_bf  = (ushort*)(oa_ws + (size_t)NQ * 768); // NQ*256 bf16
    ushort* Wv_t    = agg_bf + (size_t)NQ * 256;         // 256*256
    ushort* Woa_t   = Wv_t + 256 * 256;                  // 768*256
    ushort* Wt_t    = Woa_t + 768 * 256;                 // 256*256
    float*  bias_oa = (float*)(Wt_t + 256 * 256);        // 768 f32

    dim3 blk(256);

    prep_w<<<dim3(128, 4), blk, 0, stream>>>(
        W_value, W_off, W_attn, W_out, b_off, b_attn,
        Wv_t, Woa_t, Wt_t, bias_oa);

    // value projection: (NV,256) @ (256,256) -> f32 (A converted in staging)
    gemm_bf16<true, false, false><<<dim3((NV + 127) / 128, 4), blk, 0, stream>>>(
        value, Wv_t, b_value, nullptr, v_ws, NV, 256);
    // fused offsets+logits: (NQ,256) @ (256,768) -> f32
    gemm_bf16<true, false, false><<<dim3((NQ + 127) / 128, 12), blk, 0, stream>>>(
        query, Woa_t, bias_oa, nullptr, oa_ws, NQ, 768);
    // bilinear sampling + weighted aggregation -> bf16 agg
    sample_kernel<<<NQ, blk, 0, stream>>>(v_ws, oa_ws, rp, agg_bf);
    // output projection + residual: (NQ,256) @ (256,256) + b + query
    gemm_bf16<false, true, false><<<dim3((NQ + 127) / 128, 4), blk, 0, stream>>>(
        agg_bf, Wt_t, b_out, query, out, NQ, 256);
}